// Round 1
// baseline (338.082 us; speedup 1.0000x reference)
//
#include <hip/hip_runtime.h>
#include <stdint.h>

// ScoreAggregation: N=8192 nodes, T=4 edge types x E=131072 edges, H=4 heads.
// out_i = mean_h [ (S_total + sum_nz (e^leaky(A_ij)-1) s_j) / (N + sum_nz (e^leaky(A_ij)-1)) ]
// where A_ij[h] = c_tot*(s_i*w_src[h] + s_j*w_tgt[h]) + sum_t cnt_t*emb_term[h][t]
// Dedup of multi-edges at the same (i,j) cell is REQUIRED (nonlinearity after
// aggregation) -> hash table keyed on (i<<13)|j with byte-packed per-type counts.

#define NN 8192
#define TT 4
#define EE 131072
#define DD 32
#define HH 4
#define NEG_SLOPE 0.2f

#define HASH_BITS 20
#define HM (1u << HASH_BITS)          // 1,048,576 slots; load factor ~0.5
#define EMPTY_KEY 0xFFFFFFFFu         // real keys < 2^26, never collides

// ws layout (uint32 units):
//   [0, HM)        : hash keys
//   [HM, 2*HM)     : hash counts (4 x u8, one per edge type)
// then as float (base = (float*)ws + 2*HM):
//   [0, H*N)           : num accumulators
//   [H*N, 2*H*N)       : den accumulators
//   [2*H*N]            : S_total
//   [2*H*N+1, +H)      : w_src[H]
//   [.. +H)            : w_tgt[H]
//   [.. +H*T)          : emb_term[H][T]
#define F_NUM   0
#define F_DEN   (HH * NN)
#define F_ST    (2 * HH * NN)
#define F_WSRC  (F_ST + 1)
#define F_WTGT  (F_WSRC + HH)
#define F_EMB   (F_WTGT + HH)
#define F_TOTAL (F_EMB + HH * TT)
#define WS_WORDS (2 * HM + F_TOTAL)

__global__ void k_init(uint32_t* __restrict__ ws) {
    uint32_t stride = gridDim.x * blockDim.x;
    for (uint32_t i = blockIdx.x * blockDim.x + threadIdx.x; i < WS_WORDS; i += stride) {
        ws[i] = (i < HM) ? EMPTY_KEY : 0u;
    }
}

// Single block: head constants + S_total reduction.
__global__ void k_consts(const float* __restrict__ scores,
                         const float* __restrict__ ete,
                         const float* __restrict__ aw,
                         float* __restrict__ f) {
    __shared__ float red[256];
    int tid = threadIdx.x;
    float s = 0.f;
    for (int i = tid; i < NN; i += 256) s += scores[i];
    red[tid] = s;
    __syncthreads();
    for (int off = 128; off > 0; off >>= 1) {
        if (tid < off) red[tid] += red[tid + off];
        __syncthreads();
    }
    if (tid == 0) f[F_ST] = red[0];
    if (tid < HH) {
        f[F_WSRC + tid] = aw[tid * (DD + 2)];           // w[0]
        f[F_WTGT + tid] = aw[tid * (DD + 2) + DD + 1];  // w[D+1]
    }
    if (tid < HH * TT) {
        int h = tid / TT, t = tid % TT;
        float acc = 0.f;
        for (int d = 0; d < DD; ++d)
            acc += ete[t * DD + d] * aw[h * (DD + 2) + 1 + d];
        f[F_EMB + tid] = acc;
    }
}

__device__ __forceinline__ uint32_t hash_key(uint32_t key) {
    uint32_t h = key;
    h ^= h >> 16; h *= 0x85ebca6bu;
    h ^= h >> 13; h *= 0xc2b2ae35u;
    h ^= h >> 16;
    return h & (HM - 1);
}

__global__ void k_build(const int* __restrict__ ei,
                        uint32_t* __restrict__ keys,
                        uint32_t* __restrict__ cnts) {
    int idx = blockIdx.x * blockDim.x + threadIdx.x;
    if (idx >= TT * EE) return;
    int t = idx >> 17;            // EE = 2^17
    int e = idx & (EE - 1);
    int src = ei[(t * 2) * EE + e];
    int tgt = ei[(t * 2 + 1) * EE + e];
    uint32_t key = ((uint32_t)src << 13) | (uint32_t)tgt;   // row=src, col=tgt
    uint32_t slot = hash_key(key);
    uint32_t inc = 1u << (8 * t);
    while (true) {
        uint32_t prev = atomicCAS(&keys[slot], EMPTY_KEY, key);
        if (prev == EMPTY_KEY || prev == key) {
            atomicAdd(&cnts[slot], inc);
            break;
        }
        slot = (slot + 1) & (HM - 1);
    }
}

__global__ void k_accum(const float* __restrict__ scores,
                        const uint32_t* __restrict__ keys,
                        const uint32_t* __restrict__ cnts,
                        float* __restrict__ f) {
    // broadcast consts (same address across lanes -> scalar-cached)
    float wsrc[HH], wtgt[HH], em[HH * TT];
    for (int h = 0; h < HH; ++h) {
        wsrc[h] = f[F_WSRC + h];
        wtgt[h] = f[F_WTGT + h];
    }
    for (int k = 0; k < HH * TT; ++k) em[k] = f[F_EMB + k];

    uint32_t stride = gridDim.x * blockDim.x;
    for (uint32_t s = blockIdx.x * blockDim.x + threadIdx.x; s < HM; s += stride) {
        uint32_t key = keys[s];
        if (key == EMPTY_KEY) continue;
        uint32_t cp = cnts[s];
        float c0 = (float)(cp & 0xffu);
        float c1 = (float)((cp >> 8) & 0xffu);
        float c2 = (float)((cp >> 16) & 0xffu);
        float c3 = (float)(cp >> 24);
        float ctot = c0 + c1 + c2 + c3;
        uint32_t i = key >> 13;
        uint32_t j = key & (NN - 1);
        float si = scores[i];
        float sj = scores[j];
        #pragma unroll
        for (int h = 0; h < HH; ++h) {
            float a = ctot * (si * wsrc[h] + sj * wtgt[h])
                    + c0 * em[h * TT + 0] + c1 * em[h * TT + 1]
                    + c2 * em[h * TT + 2] + c3 * em[h * TT + 3];
            a = (a >= 0.f) ? a : NEG_SLOPE * a;
            float ex = expf(a) - 1.f;
            atomicAdd(&f[F_DEN + h * NN + i], ex);
            atomicAdd(&f[F_NUM + h * NN + i], ex * sj);
        }
    }
}

__global__ void k_final(const float* __restrict__ f, float* __restrict__ out) {
    int i = blockIdx.x * blockDim.x + threadIdx.x;
    if (i >= NN) return;
    float st = f[F_ST];
    float acc = 0.f;
    #pragma unroll
    for (int h = 0; h < HH; ++h) {
        acc += (st + f[F_NUM + h * NN + i]) / ((float)NN + f[F_DEN + h * NN + i]);
    }
    out[i] = acc * (1.f / HH);
}

extern "C" void kernel_launch(void* const* d_in, const int* in_sizes, int n_in,
                              void* d_out, int out_size, void* d_ws, size_t ws_size,
                              hipStream_t stream) {
    const float* scores = (const float*)d_in[0];
    const float* ete    = (const float*)d_in[1];
    const int*   ei     = (const int*)d_in[2];
    const float* aw     = (const float*)d_in[3];
    float* out = (float*)d_out;
    uint32_t* ws = (uint32_t*)d_ws;
    float* f = (float*)(ws + 2 * HM);

    k_init<<<2048, 256, 0, stream>>>(ws);
    k_consts<<<1, 256, 0, stream>>>(scores, ete, aw, f);
    k_build<<<(TT * EE) / 256, 256, 0, stream>>>(ei, ws, ws + HM);
    k_accum<<<2048, 256, 0, stream>>>(scores, ws, ws + HM, f);
    k_final<<<NN / 256, 256, 0, stream>>>(f, out);
}

// Round 2
// 113.236 us; speedup vs baseline: 2.9857x; 2.9857x over previous
//
#include <hip/hip_runtime.h>
#include <stdint.h>

// ScoreAggregation: N=8192 nodes, T=4 edge types x E=131072 edges, H=4 heads.
// out_i = mean_h [ (S_total + sum_nz (e^leaky(A_ij)-1) s_j) / (N + sum_nz (e^leaky(A_ij)-1)) ]
// A_ij[h] = c_tot*(s_i*w_src[h] + s_j*w_tgt[h]) + sum_t cnt_t*emb_term[h][t]
// Dedup of multi-edges at (i,j) is REQUIRED (nonlinearity after aggregation).
// Row-segmented hash: row i owns slots [i*256, i*256+256). Packed slot word:
// bits[12:0]=tgt, [16:13]=cnt_t0, [20:17]=cnt_t1, [24:21]=cnt_t2, [28:25]=cnt_t3.
// One wave per row in the accumulate phase -> zero atomics there.

#define NN 8192
#define TT 4
#define EE 131072
#define DD 32
#define HH 4
#define NEG_SLOPE 0.2f

#define SEG 256
#define SEG_SHIFT 8
#define HM (NN * SEG)            // 2M slots, 8 MB
#define EMPTY 0xFFFFFFFFu        // occupied words have bits 31:29 == 0

// ws: [0, HM) u32 table; then floats f[25]:
// f[0]=S_total, f[1..4]=w_src[h], f[5..8]=w_tgt[h], f[9+h*4+t]=emb_term[h][t]

__global__ void k_init(uint32_t* __restrict__ tab,
                       const float* __restrict__ scores,
                       const float* __restrict__ ete,
                       const float* __restrict__ aw,
                       float* __restrict__ f) {
    uint32_t stride = gridDim.x * blockDim.x;
    for (uint32_t i = blockIdx.x * blockDim.x + threadIdx.x; i < HM; i += stride)
        tab[i] = EMPTY;
    if (blockIdx.x == 0) {
        __shared__ float red[256];
        int tid = threadIdx.x;
        float s = 0.f;
        for (int i = tid; i < NN; i += 256) s += scores[i];
        red[tid] = s;
        __syncthreads();
        for (int off = 128; off > 0; off >>= 1) {
            if (tid < off) red[tid] += red[tid + off];
            __syncthreads();
        }
        if (tid == 0) f[0] = red[0];
        if (tid < HH) {
            f[1 + tid] = aw[tid * (DD + 2)];            // w[0]
            f[5 + tid] = aw[tid * (DD + 2) + DD + 1];   // w[D+1]
        }
        if (tid < HH * TT) {
            int h = tid / TT, t = tid % TT;
            float acc = 0.f;
            for (int d = 0; d < DD; ++d)
                acc += ete[t * DD + d] * aw[h * (DD + 2) + 1 + d];
            f[9 + tid] = acc;
        }
    }
}

__global__ void k_build(const int* __restrict__ ei, uint32_t* __restrict__ tab) {
    int idx = blockIdx.x * blockDim.x + threadIdx.x;     // exactly T*E threads
    int t = idx >> 17;                                   // EE = 2^17
    int e = idx & (EE - 1);
    uint32_t src = (uint32_t)ei[(t * 2) * EE + e];
    uint32_t tgt = (uint32_t)ei[(t * 2 + 1) * EE + e];
    uint32_t inc = 1u << (13 + 4 * t);
    uint32_t base = src << SEG_SHIFT;
    uint32_t pos = (tgt * 2654435761u) >> 24;            // 8-bit probe start
    uint32_t fresh = tgt | inc;
    while (true) {
        uint32_t slot = base | pos;
        uint32_t cur = atomicCAS(&tab[slot], EMPTY, fresh);
        if (cur == EMPTY) return;                        // inserted fresh entry
        while ((cur & 0x1FFFu) == tgt) {                 // same cell: bump count
            uint32_t prev = atomicCAS(&tab[slot], cur, cur + inc);
            if (prev == cur) return;
            cur = prev;
        }
        pos = (pos + 1) & (SEG - 1);                     // other cell: probe on
    }
}

__device__ __forceinline__ void entry_accum(uint32_t w, float si,
                                            const float* __restrict__ scores,
                                            const float* wsrc, const float* wtgt,
                                            const float* em,
                                            float* num, float* den) {
    if (w == EMPTY) return;
    uint32_t tgt = w & 0x1FFFu;
    float c0 = (float)((w >> 13) & 15u);
    float c1 = (float)((w >> 17) & 15u);
    float c2 = (float)((w >> 21) & 15u);
    float c3 = (float)((w >> 25) & 15u);
    float ctot = c0 + c1 + c2 + c3;
    float sj = scores[tgt];
    #pragma unroll
    for (int h = 0; h < HH; ++h) {
        float a = ctot * (si * wsrc[h] + sj * wtgt[h])
                + c0 * em[h * 4 + 0] + c1 * em[h * 4 + 1]
                + c2 * em[h * 4 + 2] + c3 * em[h * 4 + 3];
        a = (a >= 0.f) ? a : NEG_SLOPE * a;
        float ex = expf(a) - 1.f;
        den[h] += ex;
        num[h] += ex * sj;
    }
}

__global__ void __launch_bounds__(256) k_accum(const float* __restrict__ scores,
                                               const uint32_t* __restrict__ tab,
                                               const float* __restrict__ f,
                                               float* __restrict__ out) {
    int wave = (int)((blockIdx.x * blockDim.x + threadIdx.x) >> 6);  // = row
    int lane = threadIdx.x & 63;
    float st = f[0];
    float wsrc[HH], wtgt[HH], em[HH * TT];
    #pragma unroll
    for (int h = 0; h < HH; ++h) { wsrc[h] = f[1 + h]; wtgt[h] = f[5 + h]; }
    #pragma unroll
    for (int k = 0; k < HH * TT; ++k) em[k] = f[9 + k];

    float si = scores[wave];
    const uint4* seg4 = (const uint4*)(tab + ((uint32_t)wave << SEG_SHIFT));
    uint4 w = seg4[lane];                 // wave covers all 256 slots, coalesced

    float num[HH] = {0.f, 0.f, 0.f, 0.f};
    float den[HH] = {0.f, 0.f, 0.f, 0.f};
    entry_accum(w.x, si, scores, wsrc, wtgt, em, num, den);
    entry_accum(w.y, si, scores, wsrc, wtgt, em, num, den);
    entry_accum(w.z, si, scores, wsrc, wtgt, em, num, den);
    entry_accum(w.w, si, scores, wsrc, wtgt, em, num, den);

    #pragma unroll
    for (int m = 32; m > 0; m >>= 1) {
        #pragma unroll
        for (int h = 0; h < HH; ++h) {
            num[h] += __shfl_xor(num[h], m, 64);
            den[h] += __shfl_xor(den[h], m, 64);
        }
    }
    if (lane == 0) {
        float acc = 0.f;
        #pragma unroll
        for (int h = 0; h < HH; ++h)
            acc += (st + num[h]) / ((float)NN + den[h]);
        out[wave] = acc * (1.f / HH);
    }
}

extern "C" void kernel_launch(void* const* d_in, const int* in_sizes, int n_in,
                              void* d_out, int out_size, void* d_ws, size_t ws_size,
                              hipStream_t stream) {
    const float* scores = (const float*)d_in[0];
    const float* ete    = (const float*)d_in[1];
    const int*   ei     = (const int*)d_in[2];
    const float* aw     = (const float*)d_in[3];
    float* out = (float*)d_out;
    uint32_t* tab = (uint32_t*)d_ws;
    float* f = (float*)(tab + HM);

    k_init<<<2048, 256, 0, stream>>>(tab, scores, ete, aw, f);
    k_build<<<(TT * EE) / 256, 256, 0, stream>>>(ei, tab);
    k_accum<<<NN / 4, 256, 0, stream>>>(scores, tab, f, out);
}

// Round 3
// 105.154 us; speedup vs baseline: 3.2151x; 1.0769x over previous
//
#include <hip/hip_runtime.h>
#include <stdint.h>

// ScoreAggregation: N=8192, T=4 x E=131072 edges, H=4 heads.
// out_i = mean_h [ (S_total + sum_nz (e^leaky(A_ij)-1) s_j) / (N + sum_nz (e^leaky(A_ij)-1)) ]
// A_ij[h] = c_tot*(s_i*w_src[h] + s_j*w_tgt[h]) + sum_t cnt_t*emb[h][t]
// Global atomics are the wall (~8k/us scattered) -> bucket edges by src>>5,
// dedup per-bucket in a 16KB LDS hash (LDS CAS), accumulate + output in-block.

#define NN 8192
#define TT 4
#define EE 131072
#define DD 32
#define HH 4
#define NEG_SLOPE 0.2f

#define NB  256          // buckets = src>>5
#define RPB 32           // rows per bucket
#define CAP 2560         // per-bucket capacity (mean 2048, +11 sigma)
#define SEG 128          // LDS hash slots per row (max distinct/row ~100)
#define EMPTY 0xFFFFFFFFu

// ws: u32 cursor[NB]; pad; float f[25] @ +NB+32... layout below.
// f[0]=S_total, f[1..4]=w_src, f[5..8]=w_tgt, f[9+h*4+t]=emb
// buf: u32[NB*CAP] packed edges: (src&31)<<15 | tgt<<2 | t

__global__ void k0(const float* __restrict__ scores,
                   const float* __restrict__ ete,
                   const float* __restrict__ aw,
                   uint32_t* __restrict__ cursor,
                   float* __restrict__ f) {
    int tid = threadIdx.x;
    if (tid < NB) cursor[tid] = 0;
    __shared__ float red[256];
    float s = 0.f;
    for (int i = tid; i < NN; i += 256) s += scores[i];
    red[tid] = s;
    __syncthreads();
    for (int off = 128; off > 0; off >>= 1) {
        if (tid < off) red[tid] += red[tid + off];
        __syncthreads();
    }
    if (tid == 0) f[0] = red[0];
    if (tid < HH) {
        f[1 + tid] = aw[tid * (DD + 2)];            // w[0]
        f[5 + tid] = aw[tid * (DD + 2) + DD + 1];   // w[D+1]
    }
    if (tid < HH * TT) {
        int h = tid / TT, t = tid % TT;
        float acc = 0.f;
        for (int d = 0; d < DD; ++d)
            acc += ete[t * DD + d] * aw[h * (DD + 2) + 1 + d];
        f[9 + tid] = acc;
    }
}

#define A_EPT 16   // edges per thread; 128 blocks x 256 thr x 16 = 524288
__global__ void __launch_bounds__(256) kA(const int* __restrict__ ei,
                                          uint32_t* __restrict__ cursor,
                                          uint32_t* __restrict__ buf) {
    __shared__ uint32_t hist[NB];
    __shared__ uint32_t baseh[NB];
    int tid = threadIdx.x;
    if (tid < NB) hist[tid] = 0;
    __syncthreads();

    uint32_t gtid = blockIdx.x * 256u + (uint32_t)tid;   // 32768 threads
    uint32_t t  = gtid >> 13;                            // 8192 threads/type
    uint32_t e0 = (gtid & 8191u) * A_EPT;
    const int4* sp = (const int4*)(ei + (size_t)(t * 2) * EE + e0);
    const int4* tp = (const int4*)(ei + (size_t)(t * 2 + 1) * EE + e0);

    uint32_t val[A_EPT];     // (src<<15)|(tgt<<2)|t  -- 28 bits; bucket = val>>20
    uint32_t rnk[A_EPT];
    #pragma unroll
    for (int k = 0; k < A_EPT / 4; ++k) {
        int4 s4 = sp[k];
        int4 t4 = tp[k];
        val[k*4+0] = ((uint32_t)s4.x << 15) | ((uint32_t)t4.x << 2) | t;
        val[k*4+1] = ((uint32_t)s4.y << 15) | ((uint32_t)t4.y << 2) | t;
        val[k*4+2] = ((uint32_t)s4.z << 15) | ((uint32_t)t4.z << 2) | t;
        val[k*4+3] = ((uint32_t)s4.w << 15) | ((uint32_t)t4.w << 2) | t;
    }
    #pragma unroll
    for (int k = 0; k < A_EPT; ++k)
        rnk[k] = atomicAdd(&hist[val[k] >> 20], 1u);
    __syncthreads();
    if (tid < NB) baseh[tid] = atomicAdd(&cursor[tid], hist[tid]);
    __syncthreads();
    #pragma unroll
    for (int k = 0; k < A_EPT; ++k) {
        uint32_t b = val[k] >> 20;
        buf[b * CAP + baseh[b] + rnk[k]] = val[k] & 0xFFFFFu;
    }
}

__global__ void __launch_bounds__(256) kB(const float* __restrict__ scores,
                                          const uint32_t* __restrict__ cursor,
                                          const uint32_t* __restrict__ buf,
                                          const float* __restrict__ f,
                                          float* __restrict__ out) {
    __shared__ uint32_t tab[RPB * SEG];      // 16 KB
    int tid = threadIdx.x;
    for (int i = tid; i < RPB * SEG; i += 256) tab[i] = EMPTY;

    float st = f[0];
    float wsrc[HH], wtgt[HH], em[HH * TT];
    #pragma unroll
    for (int h = 0; h < HH; ++h) { wsrc[h] = f[1 + h]; wtgt[h] = f[5 + h]; }
    #pragma unroll
    for (int k = 0; k < HH * TT; ++k) em[k] = f[9 + k];
    __syncthreads();

    uint32_t b = blockIdx.x;
    uint32_t n = cursor[b];
    if (n > CAP) n = CAP;                    // safety clamp
    const uint32_t* bb = buf + b * CAP;

    for (uint32_t i = tid; i < n; i += 256) {
        uint32_t v   = bb[i];
        uint32_t row = v >> 15;
        uint32_t tgt = (v >> 2) & 8191u;
        uint32_t tt  = v & 3u;
        uint32_t inc = 1u << (13 + 4 * tt);
        uint32_t fresh = tgt | inc;
        uint32_t pos = (tgt * 2654435761u) >> 25;    // 7-bit probe start
        uint32_t base = row * SEG;
        while (true) {
            uint32_t cur = atomicCAS(&tab[base + pos], EMPTY, fresh);
            if (cur == EMPTY) break;                 // fresh insert
            bool done = false;
            while ((cur & 0x1FFFu) == tgt) {         // same cell: bump count
                uint32_t prev = atomicCAS(&tab[base + pos], cur, cur + inc);
                if (prev == cur) { done = true; break; }
                cur = prev;
            }
            if (done) break;
            pos = (pos + 1) & (SEG - 1);             // probe on
        }
    }
    __syncthreads();

    int wave = tid >> 6, lane = tid & 63;
    #pragma unroll
    for (int rr = 0; rr < 8; ++rr) {
        int r = wave * 8 + rr;
        float si = scores[b * RPB + r];
        float num[HH] = {0.f, 0.f, 0.f, 0.f};
        float den[HH] = {0.f, 0.f, 0.f, 0.f};
        #pragma unroll
        for (int half = 0; half < 2; ++half) {
            uint32_t w = tab[r * SEG + half * 64 + lane];
            if (w != EMPTY) {
                uint32_t tgt = w & 0x1FFFu;
                float c0 = (float)((w >> 13) & 15u);
                float c1 = (float)((w >> 17) & 15u);
                float c2 = (float)((w >> 21) & 15u);
                float c3 = (float)((w >> 25) & 15u);
                float ctot = c0 + c1 + c2 + c3;
                float sj = scores[tgt];
                #pragma unroll
                for (int h = 0; h < HH; ++h) {
                    float a = ctot * (si * wsrc[h] + sj * wtgt[h])
                            + c0 * em[h * 4 + 0] + c1 * em[h * 4 + 1]
                            + c2 * em[h * 4 + 2] + c3 * em[h * 4 + 3];
                    a = (a >= 0.f) ? a : NEG_SLOPE * a;
                    float ex = expf(a) - 1.f;
                    den[h] += ex;
                    num[h] += ex * sj;
                }
            }
        }
        #pragma unroll
        for (int m = 32; m > 0; m >>= 1) {
            #pragma unroll
            for (int h = 0; h < HH; ++h) {
                num[h] += __shfl_xor(num[h], m, 64);
                den[h] += __shfl_xor(den[h], m, 64);
            }
        }
        if (lane == 0) {
            float acc = 0.f;
            #pragma unroll
            for (int h = 0; h < HH; ++h)
                acc += (st + num[h]) / ((float)NN + den[h]);
            out[b * RPB + r] = acc * (1.f / HH);
        }
    }
}

extern "C" void kernel_launch(void* const* d_in, const int* in_sizes, int n_in,
                              void* d_out, int out_size, void* d_ws, size_t ws_size,
                              hipStream_t stream) {
    const float* scores = (const float*)d_in[0];
    const float* ete    = (const float*)d_in[1];
    const int*   ei     = (const int*)d_in[2];
    const float* aw     = (const float*)d_in[3];
    float* out = (float*)d_out;

    uint32_t* cursor = (uint32_t*)d_ws;
    float*    f      = (float*)(cursor + NB);        // 25 floats used
    uint32_t* buf    = cursor + NB + 64;             // padded past f

    k0<<<1, 256, 0, stream>>>(scores, ete, aw, cursor, f);
    kA<<<128, 256, 0, stream>>>(ei, cursor, buf);
    kB<<<NB, 256, 0, stream>>>(scores, cursor, buf, f, out);
}

// Round 4
// 92.525 us; speedup vs baseline: 3.6540x; 1.1365x over previous
//
#include <hip/hip_runtime.h>
#include <stdint.h>

// ScoreAggregation: N=8192, T=4 x E=131072 edges, H=4 heads.
// out_i = mean_h [ (S_total + sum_nz (e^leaky(A_ij)-1) s_j) / (N + sum_nz (e^leaky(A_ij)-1)) ]
// A_ij[h] = c_tot*(s_i*w_src[h] + s_j*w_tgt[h]) + sum_t cnt_t*emb[h][t]
// Dedup at (i,j) required (nonlinearity after aggregation).
// r3 lesson: kB at 1 block/CU (16KB LDS) = zero latency hiding (VALUBusy 10%).
// -> NB=1024 buckets (src>>3), 4KB LDS hash, 4 blocks/CU; deterministic
//    per-(bucket,block) sub-runs in buf so NO global atomics anywhere.

#define NN 8192
#define TT 4
#define EE 131072
#define DD 32
#define HH 4
#define NEG_SLOPE 0.2f

#define NB    1024       // buckets = src>>3
#define RPB   8          // rows per bucket
#define SEG   128        // LDS hash slots per row (max distinct/row ~100)
#define ABLK  128        // kA scatter blocks
#define CAPBB 20         // capacity per (bucket, kA-block) sub-run; mean 4
#define A_EPT 16         // edges/thread: 128 blk x 256 thr x 16 = 524288
#define EMPTY 0xFFFFFFFFu

// ws layout:
//   cnt : u8 [NB*ABLK]                  @ 0        (131072 B)
//   f   : float[25]                     @ 131072   (pad to +1024)
//   buf : u32[NB*ABLK*CAPBB]            @ 132096   (~10.5 MB)
// f: f[0]=S_total, f[1..4]=w_src, f[5..8]=w_tgt, f[9+h*4+t]=emb

__global__ void __launch_bounds__(256) kA(const int* __restrict__ ei,
                                          const float* __restrict__ scores,
                                          const float* __restrict__ ete,
                                          const float* __restrict__ aw,
                                          uint8_t* __restrict__ cnt,
                                          uint32_t* __restrict__ buf,
                                          float* __restrict__ f) {
    int tid = threadIdx.x;
    if (blockIdx.x == ABLK) {            // consts block (replaces k0)
        __shared__ float red[256];
        float s = 0.f;
        for (int i = tid; i < NN; i += 256) s += scores[i];
        red[tid] = s;
        __syncthreads();
        for (int off = 128; off > 0; off >>= 1) {
            if (tid < off) red[tid] += red[tid + off];
            __syncthreads();
        }
        if (tid == 0) f[0] = red[0];
        if (tid < HH) {
            f[1 + tid] = aw[tid * (DD + 2)];            // w[0]
            f[5 + tid] = aw[tid * (DD + 2) + DD + 1];   // w[D+1]
        }
        if (tid < HH * TT) {
            int h = tid / TT, t = tid % TT;
            float acc = 0.f;
            for (int d = 0; d < DD; ++d)
                acc += ete[t * DD + d] * aw[h * (DD + 2) + 1 + d];
            f[9 + tid] = acc;
        }
        return;
    }

    __shared__ uint32_t hist[NB];
    for (int i = tid; i < NB; i += 256) hist[i] = 0;
    __syncthreads();

    uint32_t gtid = blockIdx.x * 256u + (uint32_t)tid;   // [0, 32768)
    uint32_t t  = gtid >> 13;                            // 8192 threads/type
    uint32_t e0 = (gtid & 8191u) * A_EPT;
    const int4* sp = (const int4*)(ei + (size_t)(t * 2) * EE + e0);
    const int4* tp = (const int4*)(ei + (size_t)(t * 2 + 1) * EE + e0);

    uint32_t val[A_EPT];     // (src<<15)|(tgt<<2)|t ; bucket = val>>18
    uint32_t rnk[A_EPT];
    #pragma unroll
    for (int k = 0; k < A_EPT / 4; ++k) {
        int4 s4 = sp[k];
        int4 t4 = tp[k];
        val[k*4+0] = ((uint32_t)s4.x << 15) | ((uint32_t)t4.x << 2) | t;
        val[k*4+1] = ((uint32_t)s4.y << 15) | ((uint32_t)t4.y << 2) | t;
        val[k*4+2] = ((uint32_t)s4.z << 15) | ((uint32_t)t4.z << 2) | t;
        val[k*4+3] = ((uint32_t)s4.w << 15) | ((uint32_t)t4.w << 2) | t;
    }
    #pragma unroll
    for (int k = 0; k < A_EPT; ++k)
        rnk[k] = atomicAdd(&hist[val[k] >> 18], 1u);
    __syncthreads();

    for (int i = tid; i < NB; i += 256) {
        uint32_t c = hist[i];
        cnt[(uint32_t)i * ABLK + blockIdx.x] = (uint8_t)(c > CAPBB ? CAPBB : c);
    }
    #pragma unroll
    for (int k = 0; k < A_EPT; ++k) {
        if (rnk[k] < CAPBB) {
            uint32_t b = val[k] >> 18;
            buf[((size_t)b * ABLK + blockIdx.x) * CAPBB + rnk[k]] = val[k] & 0x3FFFFu;
        }
    }
}

__global__ void __launch_bounds__(256) kB(const float* __restrict__ scores,
                                          const uint8_t* __restrict__ cnt,
                                          const uint32_t* __restrict__ buf,
                                          const float* __restrict__ f,
                                          float* __restrict__ out) {
    __shared__ uint32_t tab[RPB * SEG];      // 4 KB
    __shared__ uint8_t  cc[ABLK];
    int tid = threadIdx.x;
    for (int i = tid; i < RPB * SEG; i += 256) tab[i] = EMPTY;
    uint32_t b = blockIdx.x;
    if (tid < ABLK) cc[tid] = cnt[b * ABLK + tid];

    float st = f[0];
    float wsrc[HH], wtgt[HH], em[HH * TT];
    #pragma unroll
    for (int h = 0; h < HH; ++h) { wsrc[h] = f[1 + h]; wtgt[h] = f[5 + h]; }
    #pragma unroll
    for (int k = 0; k < HH * TT; ++k) em[k] = f[9 + k];
    __syncthreads();

    // dedup: 2 threads per sub-run (128 runs x <=20 entries, mean 4)
    int run = tid >> 1, sub = tid & 1;
    const uint32_t* rb = buf + ((size_t)b * ABLK + run) * CAPBB;
    int c = cc[run];
    for (int i = sub; i < c; i += 2) {
        uint32_t v   = rb[i];
        uint32_t row = v >> 15;
        uint32_t tgt = (v >> 2) & 8191u;
        uint32_t tt  = v & 3u;
        uint32_t inc = 1u << (13 + 4 * tt);
        uint32_t fresh = tgt | inc;
        uint32_t pos = (tgt * 2654435761u) >> 25;    // 7-bit probe start
        uint32_t base = row * SEG;
        while (true) {
            uint32_t cur = atomicCAS(&tab[base + pos], EMPTY, fresh);
            if (cur == EMPTY) break;
            bool done = false;
            while ((cur & 0x1FFFu) == tgt) {
                uint32_t prev = atomicCAS(&tab[base + pos], cur, cur + inc);
                if (prev == cur) { done = true; break; }
                cur = prev;
            }
            if (done) break;
            pos = (pos + 1) & (SEG - 1);
        }
    }
    __syncthreads();

    // accumulate: 4 waves x 2 rows, zero atomics
    int wave = tid >> 6, lane = tid & 63;
    #pragma unroll
    for (int rr = 0; rr < 2; ++rr) {
        int r = wave * 2 + rr;
        float si = scores[b * RPB + r];
        float num[HH] = {0.f, 0.f, 0.f, 0.f};
        float den[HH] = {0.f, 0.f, 0.f, 0.f};
        #pragma unroll
        for (int half = 0; half < 2; ++half) {
            uint32_t w = tab[r * SEG + half * 64 + lane];
            if (w != EMPTY) {
                uint32_t tgt = w & 0x1FFFu;
                float c0 = (float)((w >> 13) & 15u);
                float c1 = (float)((w >> 17) & 15u);
                float c2 = (float)((w >> 21) & 15u);
                float c3 = (float)((w >> 25) & 15u);
                float ctot = c0 + c1 + c2 + c3;
                float sj = scores[tgt];
                #pragma unroll
                for (int h = 0; h < HH; ++h) {
                    float a = ctot * (si * wsrc[h] + sj * wtgt[h])
                            + c0 * em[h * 4 + 0] + c1 * em[h * 4 + 1]
                            + c2 * em[h * 4 + 2] + c3 * em[h * 4 + 3];
                    a = (a >= 0.f) ? a : NEG_SLOPE * a;
                    float ex = expf(a) - 1.f;
                    den[h] += ex;
                    num[h] += ex * sj;
                }
            }
        }
        #pragma unroll
        for (int m = 32; m > 0; m >>= 1) {
            #pragma unroll
            for (int h = 0; h < HH; ++h) {
                num[h] += __shfl_xor(num[h], m, 64);
                den[h] += __shfl_xor(den[h], m, 64);
            }
        }
        if (lane == 0) {
            float acc = 0.f;
            #pragma unroll
            for (int h = 0; h < HH; ++h)
                acc += (st + num[h]) / ((float)NN + den[h]);
            out[b * RPB + r] = acc * (1.f / HH);
        }
    }
}

extern "C" void kernel_launch(void* const* d_in, const int* in_sizes, int n_in,
                              void* d_out, int out_size, void* d_ws, size_t ws_size,
                              hipStream_t stream) {
    const float* scores = (const float*)d_in[0];
    const float* ete    = (const float*)d_in[1];
    const int*   ei     = (const int*)d_in[2];
    const float* aw     = (const float*)d_in[3];
    float* out = (float*)d_out;

    uint8_t*  cnt = (uint8_t*)d_ws;
    float*    f   = (float*)((char*)d_ws + NB * ABLK);
    uint32_t* buf = (uint32_t*)((char*)d_ws + NB * ABLK + 1024);

    kA<<<ABLK + 1, 256, 0, stream>>>(ei, scores, ete, aw, cnt, buf, f);
    kB<<<NB, 256, 0, stream>>>(scores, cnt, buf, f, out);
}